// Round 1
// baseline (260.556 us; speedup 1.0000x reference)
//
#include <hip/hip_runtime.h>
#include <hip/hip_bf16.h>
#include <stdint.h>

#define N_NODES_C 131072
#define B_C       16384
#define IN_C      1024
#define OUT_C     512
#define NC_C      16

typedef short s16x8 __attribute__((ext_vector_type(8)));
typedef float f32x4 __attribute__((ext_vector_type(4)));

__device__ __forceinline__ unsigned short f2bf(float f) {
  union { float f; unsigned u; } v; v.f = f;
  unsigned u = v.u;
  unsigned r = (u + 0x7fffu + ((u >> 16) & 1u)) >> 16;  // RNE
  return (unsigned short)r;
}

__device__ __forceinline__ void async_cp16(void* lds, const void* g) {
  __builtin_amdgcn_global_load_lds(
      (const __attribute__((address_space(1))) unsigned int*)g,
      (__attribute__((address_space(3))) unsigned int*)lds, 16, 0, 0);
}

// ---------------- W_experts f32 -> bf16 ----------------
__global__ __launch_bounds__(256) void k_cvt(const float* __restrict__ W,
                                             unsigned short* __restrict__ Wb) {
  const int i = (blockIdx.x * 256 + threadIdx.x) * 4;  // grid sized exactly
  float4 v = *(const float4*)&W[i];
  ushort4 h;
  h.x = f2bf(v.x); h.y = f2bf(v.y); h.z = f2bf(v.z); h.w = f2bf(v.w);
  *(ushort4*)&Wb[i] = h;
}

// ---------------- gather ego rows, cast to bf16, route (fp32 argmax) -------
__global__ __launch_bounds__(512) void k_route(
    const float* __restrict__ gnn_x, const float* __restrict__ Wc,
    const int* __restrict__ batch, const int* __restrict__ ego_idx,
    unsigned short* __restrict__ ds_bf16, int* __restrict__ cidx) {
  __shared__ float wc[NC_C * IN_C];  // 64 KiB
  const int t = threadIdx.x;
  for (int i = t * 4; i < NC_C * IN_C; i += 512 * 4)
    *(float4*)&wc[i] = *(const float4*)&Wc[i];
  __syncthreads();

  const int w = t >> 6, l = t & 63;
  const int gbase = blockIdx.x * 32 + w * 4;  // 32 rows/block, 4 per wave
  for (int rr = 0; rr < 4; ++rr) {
    const int g = gbase + rr;
    // lower_bound of g in sorted batch (searchsorted 'left')
    int lo = 0, hi = N_NODES_C;
    while (lo < hi) { int mid = (lo + hi) >> 1; if (batch[mid] < g) lo = mid + 1; else hi = mid; }
    const long src = ((long)lo + (long)ego_idx[g]) * IN_C;

    float4 xv[4];
    #pragma unroll
    for (int j = 0; j < 4; ++j) xv[j] = *(const float4*)&gnn_x[src + j * 256 + l * 4];

    #pragma unroll
    for (int j = 0; j < 4; ++j) {
      ushort4 h;
      h.x = f2bf(xv[j].x); h.y = f2bf(xv[j].y); h.z = f2bf(xv[j].z); h.w = f2bf(xv[j].w);
      *(ushort4*)&ds_bf16[(size_t)g * IN_C + j * 256 + l * 4] = h;
    }

    float sc[NC_C];
    #pragma unroll
    for (int c = 0; c < NC_C; ++c) {
      float a = 0.f;
      #pragma unroll
      for (int j = 0; j < 4; ++j) {
        float4 wv = *(const float4*)&wc[c * IN_C + j * 256 + l * 4];
        a += xv[j].x * wv.x + xv[j].y * wv.y + xv[j].z * wv.z + xv[j].w * wv.w;
      }
      #pragma unroll
      for (int off = 32; off > 0; off >>= 1) a += __shfl_xor(a, off, 64);
      sc[c] = a;
    }
    if (l == 0) {
      int best = 0; float bv = sc[0];
      #pragma unroll
      for (int c = 1; c < NC_C; ++c) if (sc[c] > bv) { bv = sc[c]; best = c; }  // strict >: first-max, matches np
      cidx[g] = best;
    }
  }
}

// ---------------- counting-sort scatter into padded per-expert lists -------
__global__ __launch_bounds__(256) void k_scatter(const int* __restrict__ cidx,
                                                 int* __restrict__ cursors,
                                                 int* __restrict__ rows_pad) {
  const int g = blockIdx.x * 256 + threadIdx.x;
  const int c = cidx[g];
  const int p = atomicAdd(&cursors[c], 1);
  rows_pad[c * B_C + p] = g;
}

// ---------------- grouped GEMM: out[rid] = dsx[rid] @ W[e]^T ---------------
// tile 64x64, BK=64, 4 waves of 32x32, mfma_f32_16x16x32_bf16,
// global_load_lds(16B) with pre-swizzled source, XOR-swizzled ds_read_b128.
__global__ __launch_bounds__(256) void k_gemm(
    const unsigned short* __restrict__ dsx, const unsigned short* __restrict__ Wb,
    const int* __restrict__ rows_pad, const int* __restrict__ cnts,
    float* __restrict__ out) {
  const int e = blockIdx.z;
  const int cnt = cnts[e];
  const int m0 = blockIdx.y * 64;
  if (m0 >= cnt) return;  // early-exit: worst-case grid
  const int n0 = blockIdx.x * 64;

  __shared__ unsigned short Al[2][64 * 64];
  __shared__ unsigned short Bl[2][64 * 64];
  __shared__ int rid_s[64];

  const int t = threadIdx.x;
  const int w = t >> 6, l = t & 63;

  if (t < 64) rid_s[t] = rows_pad[e * B_C + m0 + t];

  // staging: thread covers row r0 (issue 0) and r0+32 (issue 1); 16B per lane.
  const int r0  = w * 8 + (l >> 3);                 // 0..31
  const int swz = (((l & 7) ^ (l >> 3)) << 4);      // pre-swizzled source col-byte
  const int ra0 = rows_pad[e * B_C + m0 + r0];
  const int ra1 = rows_pad[e * B_C + m0 + r0 + 32];
  const char* aptr0 = (const char*)dsx + (size_t)(ra0 < 0 ? 0 : ra0) * (IN_C * 2) + swz;
  const char* aptr1 = (const char*)dsx + (size_t)(ra1 < 0 ? 0 : ra1) * (IN_C * 2) + swz;
  const char* bptr0 = (const char*)Wb + (size_t)(e * OUT_C + n0 + r0)      * (IN_C * 2) + swz;
  const char* bptr1 = (const char*)Wb + (size_t)(e * OUT_C + n0 + r0 + 32) * (IN_C * 2) + swz;

  const f32x4 fz = {0.f, 0.f, 0.f, 0.f};
  f32x4 acc[2][2];
  #pragma unroll
  for (int mi = 0; mi < 2; ++mi)
    #pragma unroll
    for (int ni = 0; ni < 2; ++ni) acc[mi][ni] = fz;

  const int NKT = IN_C / 64;  // 16 k-tiles

  {  // prologue: stage kt=0 into buf 0
    char* ab = (char*)&Al[0][0] + w * 1024;
    char* bb = (char*)&Bl[0][0] + w * 1024;
    async_cp16(ab,        aptr0);
    async_cp16(ab + 4096, aptr1);
    async_cp16(bb,        bptr0);
    async_cp16(bb + 4096, bptr1);
  }
  __syncthreads();

  const int wm = w >> 1, wn = w & 1;
  const int lrow = l & 15, kg = l >> 4;

  int cur = 0;
  for (int kt = 0; kt < NKT; ++kt) {
    if (kt + 1 < NKT) {  // stage next k-tile into other buffer
      const size_t ko = (size_t)(kt + 1) * 128;
      char* ab = (char*)&Al[cur ^ 1][0] + w * 1024;
      char* bb = (char*)&Bl[cur ^ 1][0] + w * 1024;
      async_cp16(ab,        aptr0 + ko);
      async_cp16(ab + 4096, aptr1 + ko);
      async_cp16(bb,        bptr0 + ko);
      async_cp16(bb + 4096, bptr1 + ko);
    }
    #pragma unroll
    for (int ks = 0; ks < 2; ++ks) {
      const int cb = ks * 64 + kg * 16;  // col-byte base of this lane's 8 bf16
      s16x8 a[2], b[2];
      #pragma unroll
      for (int mi = 0; mi < 2; ++mi) {
        const int row = wm * 32 + mi * 16 + lrow;
        a[mi] = *(const s16x8*)((const char*)&Al[cur][0] + row * 128 + (cb ^ ((row & 7) << 4)));
      }
      #pragma unroll
      for (int ni = 0; ni < 2; ++ni) {
        const int row = wn * 32 + ni * 16 + lrow;
        b[ni] = *(const s16x8*)((const char*)&Bl[cur][0] + row * 128 + (cb ^ ((row & 7) << 4)));
      }
      #pragma unroll
      for (int mi = 0; mi < 2; ++mi)
        #pragma unroll
        for (int ni = 0; ni < 2; ++ni)
          acc[mi][ni] = __builtin_amdgcn_mfma_f32_16x16x32_bf16(a[mi], b[ni], acc[mi][ni], 0, 0, 0);
    }
    __syncthreads();
    cur ^= 1;
  }

  // epilogue: C row = (l>>4)*4+reg (m side), col = l&15 (n side)  [m89 layout]
  #pragma unroll
  for (int mi = 0; mi < 2; ++mi) {
    #pragma unroll
    for (int reg = 0; reg < 4; ++reg) {
      const int rloc = wm * 32 + mi * 16 + kg * 4 + reg;
      const int rid = rid_s[rloc];
      if (rid >= 0) {
        #pragma unroll
        for (int ni = 0; ni < 2; ++ni)
          out[(size_t)rid * OUT_C + n0 + wn * 32 + ni * 16 + lrow] = acc[mi][ni][reg];
      }
    }
  }
}

extern "C" void kernel_launch(void* const* d_in, const int* in_sizes, int n_in,
                              void* d_out, int out_size, void* d_ws, size_t ws_size,
                              hipStream_t stream) {
  const float* gnn_x     = (const float*)d_in[0];
  const float* Wc        = (const float*)d_in[1];
  const float* W_experts = (const float*)d_in[2];
  const int*   batch     = (const int*)d_in[3];
  const int*   ego_idx   = (const int*)d_in[4];
  float* out = (float*)d_out;

  uint8_t* ws = (uint8_t*)d_ws;
  unsigned short* ds_bf16 = (unsigned short*)ws;                 // 33,554,432 B
  unsigned short* W_bf16  = (unsigned short*)(ws + 33554432);    // 16,777,216 B
  int* cidx     = (int*)(ws + 50331648);                         // 65,536 B
  int* cursors  = (int*)(ws + 50397184);                         // 64 B (padded)
  int* rows_pad = (int*)(ws + 50397696);                         // 1,048,576 B

  hipMemsetAsync(cursors, 0, 64, stream);
  hipMemsetAsync(rows_pad, 0xFF, NC_C * B_C * sizeof(int), stream);

  k_cvt<<<dim3(NC_C * OUT_C * IN_C / 1024), dim3(256), 0, stream>>>(W_experts, W_bf16);
  k_route<<<dim3(B_C / 32), dim3(512), 0, stream>>>(gnn_x, Wc, batch, ego_idx, ds_bf16, cidx);
  k_scatter<<<dim3(B_C / 256), dim3(256), 0, stream>>>(cidx, cursors, rows_pad);
  k_gemm<<<dim3(OUT_C / 64, B_C / 64, NC_C), dim3(256), 0, stream>>>(ds_bf16, W_bf16, rows_pad, cursors, out);
}